// Round 17
// baseline (292.266 us; speedup 1.0000x reference)
//
#include <hip/hip_runtime.h>
#include <hip/hip_bf16.h>

typedef __attribute__((ext_vector_type(8))) short short8;
typedef __attribute__((ext_vector_type(4))) float f32x4;

#define MFMA16(a,b,c) __builtin_amdgcn_mfma_f32_16x16x32_bf16((a),(b),(c),0,0,0)

constexpr int BHn = 32;     // B*NH
constexpr int Tn  = 2048;
constexpr int Nn  = 512;
constexpr int Dn  = 128;
constexpr int CHn = 128;    // chunk length
constexpr int NCH = Tn / CHn;   // 16
constexpr int UDS = 16 * 512;   // shorts per (cc,dch) U/Sst slot (SbT-swizzled image)

static __device__ __forceinline__ unsigned short f2b(float x){
  __hip_bfloat16 h = __float2bfloat16(x);
  return *reinterpret_cast<unsigned short*>(&h);
}
static __device__ __forceinline__ float b2f(unsigned short u){
  unsigned v = (unsigned)u << 16;
  float f;
  __builtin_memcpy(&f, &v, 4);
  return f;
}

// ---------------- Kernel 1: RoPE(Q) -> bf16 row-major QR ----------------
__global__ __launch_bounds__(256) void rope_k(const float* __restrict__ Q,
                                              const float* __restrict__ freqs,
                                              unsigned short* __restrict__ QR){
  int gid = blockIdx.x * 256 + threadIdx.x;
  int np  = gid & 255;
  int t   = gid >> 8;
  float tf = (float)t;
  float f1 = freqs[np], f2 = freqs[np + 256];
  float s1, c1, s2, c2;
  sincosf(tf * f1, &s1, &c1);
  sincosf(tf * f2, &s2, &c2);
  size_t off = (size_t)t * Nn + np;
  for (int bh = 0; bh < BHn; ++bh){
    size_t base = (size_t)bh * Tn * Nn + off;
    float q1 = Q[base], q2 = Q[base + 256];
    QR[base]       = f2b(q1 * c1 - q2 * s1);
    QR[base + 256] = f2b(q2 * c2 + q1 * s2);
  }
}

// ---------------- fragment loaders ----------------
// swizzled loader (LDS or global swizzled image): col ^= (row&7)<<3 (bits 3-5 only)
__device__ __forceinline__ short8 ldfrag(const unsigned short* buf, int rowbase, int k0, int ld, int lane){
  int row = rowbase + (lane & 15);
  int col = (k0 + ((lane >> 4) << 3)) ^ ((row & 7) << 3);
  return *reinterpret_cast<const short8*>(buf + row * ld + col);
}
// RT swizzled loader (round-4 proven): row = n, col = dt
__device__ __forceinline__ short8 ldfragT(const unsigned short* buf, int rowbase, int k0, int lane){
  int row = rowbase + (lane & 15);
  int sw = ((row & 7) ^ ((row >> 3) & 7)) << 3;
  int col = (k0 + ((lane >> 4) << 3)) ^ sw;
  return *reinterpret_cast<const short8*>(buf + row * 64 + col);
}
// global row-major frag: lane reads R[rowbase+(lane&15)][k0+(lane>>4)*8 ..+8]
__device__ __forceinline__ short8 gfrag(const unsigned short* Qc, int rowbase, int k0, int lane){
  return *reinterpret_cast<const short8*>(
      Qc + (size_t)(rowbase + (lane & 15)) * Nn + k0 + ((lane >> 4) << 3));
}

// ---------------- Kernel 2 (parallel, stage-free): full lower-tri P~ image ----------------
// Round-14 pd_k, verbatim (passed; ~45us).
__global__ __launch_bounds__(256) void pd_k(const unsigned short* __restrict__ QR,
                                            const float* __restrict__ gammap,
                                            unsigned short* __restrict__ Pt){
  __shared__ float gpow[129];
  const int tid = threadIdx.x, w = tid >> 6, lane = tid & 63;
  const int bh = blockIdx.x & 31, cc = blockIdx.x >> 5;
  if (tid < 129) gpow[tid] = powf(gammap[0], (float)tid);
  __syncthreads();
  const unsigned short* Qc = QR + (size_t)bh * Tn * Nn + (size_t)(cc * CHn) * Nn;

  int tiA, ntA, tiB, ntB;
  if      (w == 0){ tiA = 0; ntA = 1; tiB = 7; ntB = 8; }
  else if (w == 1){ tiA = 1; ntA = 2; tiB = 6; ntB = 7; }
  else if (w == 2){ tiA = 2; ntA = 3; tiB = 5; ntB = 6; }
  else            { tiA = 3; ntA = 4; tiB = 4; ntB = 5; }

  f32x4 accA[4], accB[8];
  #pragma unroll
  for (int t = 0; t < 4; ++t) accA[t] = {0.f, 0.f, 0.f, 0.f};
  #pragma unroll
  for (int t = 0; t < 8; ++t) accB[t] = {0.f, 0.f, 0.f, 0.f};

  for (int kb = 0; kb < 16; ++kb){
    int k0 = kb * 32;
    short8 faA = gfrag(Qc, tiA * 16, k0, lane);
    short8 faB = gfrag(Qc, tiB * 16, k0, lane);
    #pragma unroll
    for (int tj = 0; tj < 8; ++tj){
      short8 fb = gfrag(Qc, tj * 16, k0, lane);
      if (tj < ntA) accA[tj] = MFMA16(faA, fb, accA[tj]);
      if (tj < ntB) accB[tj] = MFMA16(faB, fb, accB[tj]);
    }
  }

  unsigned short* Pq = Pt + (size_t)(bh * NCH + cc) * (CHn * CHn);
  auto pw = [&](f32x4 pa, int ti, int tj, bool diag){
    int jg = tj * 16 + (lane & 15);
    int i0 = ti * 16 + ((lane >> 4) << 2);
    #pragma unroll
    for (int r = 0; r < 4; ++r){
      int ig = i0 + r;
      float v = (!diag || (jg < ig)) ? pa[r] * gpow[ig] : 0.f;
      Pq[ig * CHn + (jg ^ ((ig & 7) << 3))] = f2b(v);
    }
  };
  #pragma unroll
  for (int tj = 0; tj < 4; ++tj) if (tj < ntA) pw(accA[tj], tiA, tj, tj == ntA - 1);
  #pragma unroll
  for (int tj = 0; tj < 8; ++tj) if (tj < ntB) pw(accB[tj], tiB, tj, tj == ntB - 1);

  int zi[3], zj[3];
  if      (w == 0){ zi[0]=4; zj[0]=5; zi[1]=4; zj[1]=6; zi[2]=4; zj[2]=7; }
  else if (w == 1){ zi[0]=5; zj[0]=6; zi[1]=5; zj[1]=7; zi[2]=0; zj[2]=1; }
  else if (w == 2){ zi[0]=6; zj[0]=7; zi[1]=0; zj[1]=2; zi[2]=0; zj[2]=3; }
  else            { zi[0]=1; zj[0]=2; zi[1]=1; zj[1]=3; zi[2]=2; zj[2]=3; }
  #pragma unroll
  for (int z = 0; z < 3; ++z){
    int jg = zj[z] * 16 + (lane & 15);
    int i0 = zi[z] * 16 + ((lane >> 4) << 2);
    #pragma unroll
    for (int r = 0; r < 4; ++r){
      int ig = i0 + r;
      Pq[ig * CHn + (jg ^ ((ig & 7) << 3))] = 0;
    }
  }
}

// ---------------- Kernel 3 (parallel): U_c^T[d][n] = Sum_dt gamma^-dt V[dt][d] R[dt][n] --
// grid 4096 = bh + 32*cc + 512*dch; block 512 (8 waves, 4 n-tiles each).
// Round-4's RTs scatter staging + ldfragT + MFMA, per 64-dt half; writes SbT-swizzled slot.
__global__ __launch_bounds__(512) void u_k2(const unsigned short* __restrict__ QR,
                                            const float* __restrict__ V,
                                            const float* __restrict__ gammap,
                                            unsigned short* __restrict__ U){
  __shared__ __align__(16) unsigned short RTs[512 * 64];   // [n][dt] swizzled (64 KB)
  __shared__ __align__(16) unsigned short VTs[16 * 64];    // [d][dt] swizzled (2 KB)
  __shared__ float gpinv[129];
  const int tid = threadIdx.x, w = tid >> 6, lane = tid & 63;
  const int bh = blockIdx.x & 31, cc = (blockIdx.x >> 5) & 15, dch = blockIdx.x >> 9;
  const int d0 = dch * 16;
  if (tid < 129) gpinv[tid] = powf(gammap[0], -(float)tid);
  const unsigned short* Qch = QR + (size_t)bh * Tn * Nn + (size_t)(cc * CHn) * Nn;
  const float* Vch = V + ((size_t)bh * Tn + cc * CHn) * Dn;
  const int sb = w * 4;
  f32x4 st[4] = {{0.f,0.f,0.f,0.f},{0.f,0.f,0.f,0.f},{0.f,0.f,0.f,0.f},{0.f,0.f,0.f,0.f}};

  for (int h = 0; h < 2; ++h){
    __syncthreads();   // h=0: gpinv ready; h=1: half-0 consumers done before overwrite
    const unsigned short* Qh = Qch + (size_t)(h * 64) * Nn;
    #pragma unroll
    for (int i = 0; i < 4; ++i){
      int p  = tid + i * 512;
      int dt = (p >> 6) << 1, n0 = (p & 63) << 3;
      const unsigned short* src = Qh + (size_t)dt * Nn + n0;
      uint4 a = *reinterpret_cast<const uint4*>(src);
      uint4 b = *reinterpret_cast<const uint4*>(src + Nn);
      unsigned aw[4] = {a.x, a.y, a.z, a.w};
      unsigned bw[4] = {b.x, b.y, b.z, b.w};
      #pragma unroll
      for (int e = 0; e < 8; ++e){
        int n = n0 + e;
        unsigned lo = (e & 1) ? (aw[e >> 1] >> 16) : (aw[e >> 1] & 0xffffu);
        unsigned hi = (e & 1) ? (bw[e >> 1] >> 16) : (bw[e >> 1] & 0xffffu);
        int sw = ((n & 7) ^ ((n >> 3) & 7)) << 3;
        *reinterpret_cast<unsigned*>(&RTs[n * 64 + (dt ^ sw)]) = lo | (hi << 16);
      }
    }
    {
      int dtv = tid >> 3, dp = (tid & 7) << 1;
      const float* vp = Vch + (size_t)(h * 64 + dtv) * Dn + d0 + dp;
      float sc = gpinv[h * 64 + dtv];
      VTs[ dp      * 64 + (dtv ^ (( dp      & 7) << 3))] = f2b(vp[0] * sc);
      VTs[(dp + 1) * 64 + (dtv ^ (((dp + 1) & 7) << 3))] = f2b(vp[1] * sc);
    }
    __syncthreads();
    #pragma unroll
    for (int ks = 0; ks < 2; ++ks){
      short8 av = ldfrag(VTs, 0, ks * 32, 64, lane);
      #pragma unroll
      for (int j = 0; j < 4; ++j){
        short8 bn = ldfragT(RTs, (sb + j) * 16, ks * 32, lane);
        st[j] = MFMA16(av, bn, st[j]);
      }
    }
  }

  unsigned short* Uslot = U + ((size_t)(bh * NCH + cc) * 8 + dch) * UDS;
  #pragma unroll
  for (int j = 0; j < 4; ++j){
    int n  = (sb + j) * 16 + (lane & 15);
    int dl = (lane >> 4) << 2;
    #pragma unroll
    for (int r = 0; r < 4; ++r){
      int d = dl + r;
      Uslot[d * 512 + (n ^ ((d & 7) << 3))] = f2b(st[j][r]);
    }
  }
}

// ---------------- Kernel 4 (serial, tiny): chunk-boundary state scan ----------------
// grid 256 = bh + 32*dch; block 512; thread owns 16 consecutive slot positions (32 B).
// Overwrites U slot c with S_start(c+1) (same SbT-swizzled layout); writes Sfin.
__global__ __launch_bounds__(512) void sscan(const float* __restrict__ S_prev,
                                             const float* __restrict__ gammap,
                                             unsigned short* __restrict__ U,
                                             float* __restrict__ Sfin){
  const int tid = threadIdx.x;
  const int bh = blockIdx.x & 31, dch = blockIdx.x >> 5;
  const int d0 = dch * 16;
  const float g128 = powf(gammap[0], 128.0f);
  float st[16];
  #pragma unroll
  for (int e = 0; e < 16; ++e){
    int p = tid * 16 + e;
    int d_local = p >> 9, idx = p & 511;
    int n = idx ^ ((d_local & 7) << 3);
    st[e] = S_prev[((size_t)bh * Nn + n) * Dn + d0 + d_local];
  }
  for (int c = 0; c < NCH; ++c){
    unsigned short* slot = U + ((size_t)(bh * NCH + c) * 8 + dch) * UDS;
    const uint4* sp = reinterpret_cast<const uint4*>(slot + tid * 16);
    uint4 a = sp[0], b = sp[1];
    unsigned aw[8] = {a.x, a.y, a.z, a.w, b.x, b.y, b.z, b.w};
    #pragma unroll
    for (int e = 0; e < 16; ++e){
      unsigned wb = aw[e >> 1];
      unsigned short uv = (e & 1) ? (unsigned short)(wb >> 16) : (unsigned short)(wb & 0xffffu);
      st[e] = (st[e] + b2f(uv)) * g128;
    }
    unsigned ow[8];
    #pragma unroll
    for (int q = 0; q < 8; ++q)
      ow[q] = (unsigned)f2b(st[2 * q]) | ((unsigned)f2b(st[2 * q + 1]) << 16);
    uint4* dp = reinterpret_cast<uint4*>(slot + tid * 16);
    dp[0] = {ow[0], ow[1], ow[2], ow[3]};
    dp[1] = {ow[4], ow[5], ow[6], ow[7]};
  }
  #pragma unroll
  for (int e = 0; e < 16; ++e){
    int p = tid * 16 + e;
    int d_local = p >> 9, idx = p & 511;
    int n = idx ^ ((d_local & 7) << 3);
    Sfin[((size_t)bh * Nn + n) * Dn + d0 + d_local] = st[e];
  }
}

// ---------------- Kernel 5 (fully parallel): out = gamma^i * inter + intra ---------------
// grid 4096 = bh + 32*dch + 256*cc; block 512 (8 waves, i-tile w each).
// Round-13 lattn_s out path verbatim; S_start(c) from slot c-1 (or S_prev at c=0).
__global__ __launch_bounds__(512) void out_k(const unsigned short* __restrict__ QR,
                                             const unsigned short* __restrict__ Pt,
                                             const unsigned short* __restrict__ U,
                                             const float* __restrict__ V,
                                             const float* __restrict__ S_prev,
                                             const float* __restrict__ gammap,
                                             float* __restrict__ Out){
  __shared__ __align__(16) unsigned short SbTs[16 * 512];   // 16 KB
  __shared__ __align__(16) unsigned short VTs[16 * 128];    // 4 KB
  __shared__ float gpow[129], gpinv[129];
  const int tid = threadIdx.x, w = tid >> 6, lane = tid & 63;
  const int bh = blockIdx.x & 31, dch = (blockIdx.x >> 5) & 7, cc = blockIdx.x >> 8;
  const int d0 = dch * 16;
  const float g = gammap[0];
  if (tid < 129){
    gpow[tid]  = powf(g,  (float)tid);
    gpinv[tid] = powf(g, -(float)tid);
  }
  // SbTs = bf16(S_start(cc))^T, swizzled
  if (cc == 0){
    #pragma unroll
    for (int e = 0; e < 16; ++e){
      int p = tid * 16 + e;
      int d_local = p >> 9, idx = p & 511;
      int n = idx ^ ((d_local & 7) << 3);
      SbTs[p] = f2b(S_prev[((size_t)bh * Nn + n) * Dn + d0 + d_local]);
    }
  } else {
    const uint4* sp = reinterpret_cast<const uint4*>(
        U + ((size_t)(bh * NCH + (cc - 1)) * 8 + dch) * UDS);
    uint4* db = reinterpret_cast<uint4*>(SbTs);
    db[tid]       = sp[tid];
    db[tid + 512] = sp[tid + 512];
  }
  __syncthreads();   // gpinv ready
  {
    int dtv = tid >> 2, dp0 = (tid & 3) << 2;
    f32x4 v4 = *reinterpret_cast<const f32x4*>(
        V + ((size_t)bh * Tn + cc * CHn + dtv) * Dn + d0 + dp0);
    float sc = gpinv[dtv];
    #pragma unroll
    for (int r = 0; r < 4; ++r){
      int d = dp0 + r;
      VTs[d * 128 + (dtv ^ ((d & 7) << 3))] = f2b(v4[r] * sc);
    }
  }
  __syncthreads();

  const unsigned short* Qc = QR + (size_t)bh * Tn * Nn + (size_t)(cc * CHn) * Nn;
  const unsigned short* Pq = Pt + (size_t)(bh * NCH + cc) * (CHn * CHn);
  f32x4 o = {0.f, 0.f, 0.f, 0.f};
  for (int kb = 0; kb < 16; ++kb){
    int k0 = kb * 32;
    short8 fs = ldfrag(SbTs, 0, k0, 512, lane);
    short8 fi = gfrag(Qc, w * 16, k0, lane);
    o = MFMA16(fs, fi, o);
  }
  float gi = gpow[w * 16 + (lane & 15)];
  #pragma unroll
  for (int r = 0; r < 4; ++r) o[r] *= gi;
  const int nks = (w >> 1) + 1;   // intra cols j < (w+1)*16 <= nks*32
  #pragma unroll
  for (int ks = 0; ks < 4; ++ks) if (ks < nks){
    short8 av = ldfrag(VTs, 0, ks * 32, 128, lane);
    short8 bp = ldfrag(Pq, w * 16, ks * 32, CHn, lane);
    o = MFMA16(av, bp, o);
  }
  int ti = cc * CHn + w * 16 + (lane & 15);
  *reinterpret_cast<f32x4*>(
      Out + (size_t)bh * Tn * Dn + (size_t)ti * Dn + d0 + ((lane >> 4) << 2)) = o;
}

extern "C" void kernel_launch(void* const* d_in, const int* in_sizes, int n_in,
                              void* d_out, int out_size, void* d_ws, size_t ws_size,
                              hipStream_t stream){
  const float* Q      = (const float*)d_in[0];
  const float* V      = (const float*)d_in[1];
  const float* S_prev = (const float*)d_in[2];
  const float* freqs  = (const float*)d_in[3];
  const float* gamma  = (const float*)d_in[4];
  float* Out  = (float*)d_out;
  float* Sfin = Out + (size_t)BHn * Tn * Dn;

  unsigned short* QR = (unsigned short*)d_ws;                 // 67 MB bf16
  unsigned short* Pt = QR + (size_t)BHn * Tn * Nn;            // +16.8 MB P~ images
  unsigned short* U  = Pt + (size_t)BHn * NCH * CHn * CHn;    // +67 MB U/Sst slots

  rope_k<<<2048, 256, 0, stream>>>(Q, freqs, QR);
  pd_k<<<512, 256, 0, stream>>>(QR, gamma, Pt);
  u_k2<<<4096, 512, 0, stream>>>(QR, V, gamma, U);
  sscan<<<256, 512, 0, stream>>>(S_prev, gamma, U, Sfin);
  out_k<<<4096, 512, 0, stream>>>(QR, Pt, U, V, S_prev, gamma, Out);
}